// Round 6
// baseline (97.841 us; speedup 1.0000x reference)
//
#include <hip/hip_runtime.h>
#include <math.h>

// ---------------- constants (match reference, f32-cast like np.float32) -----
namespace {
constexpr float DTf     = 0.01f;
constexpr float GAMMA_F = 0.103f;
constexpr float DRIVE   = 0.1f;
constexpr float COUPLE  = 0.1f;
constexpr float DAMP    = 0.01f;
constexpr float ENTRAIN = 0.1f;
constexpr float EXT_SC  = 0.1f;

constexpr double PHI    = 1.618033988749895;
constexpr double TWO_PI = 6.283185307179586476925287;
constexpr double PHI2   = PHI * PHI;
constexpr double PHI4   = PHI2 * PHI2;
constexpr double PHI5   = PHI4 * PHI;
constexpr double PHI7   = PHI5 * PHI2;
constexpr double PHI11  = PHI7 * PHI4;

constexpr float OMEGA_D = (float)(TWO_PI / (40.0 * PHI11));
constexpr float OMEGA_T = (float)(TWO_PI / (40.0 * PHI7));
constexpr float OMEGA_Q = (float)(TWO_PI / (40.0 * PHI5));
constexpr float DT_OM_D = DTf * OMEGA_D;
constexpr float DT_OM_T = DTf * OMEGA_T;
constexpr float DT_OM_Q = DTf * OMEGA_Q;

constexpr int BLOCK = 256;
constexpr int RPB   = 512;               // rows per block (2 per thread)
constexpr int PPAD  = 21;                // LDS floats per pair (20 + 1 pad)

typedef float f32x4 __attribute__((ext_vector_type(4)));
}

// One row. o[0..9] = {d0,d1,t0,t1,t2,q0..q3,mean_phase}
// NOTE: D-path numerics (sinf/cosf/atan2f) must stay EXACTLY as the passing
// version (absmax 0.0430 vs threshold 0.0628; near-antipodal d_phase rows
// amplify ulp-level trig differences). T/Q use __sinf.
__device__ __forceinline__ void row_compute(
    float e,
    float dz0, float dz1, float dp0, float dp1,
    const float* tzr, const float* tpr,
    const float* qzr, const float* qpr,
    const float* Tm, const float* Qm, float tqc,
    float* o)
{
    const float ex = EXT_SC * e;

    const float dpn0 = dp0 + DT_OM_D;
    const float dpn1 = dp1 + DT_OM_D;
    const float s0 = sinf(dpn0), c0 = cosf(dpn0);
    const float s1 = sinf(dpn1), c1 = cosf(dpn1);
    const float mp = atan2f(0.5f * (s0 + s1), 0.5f * (c0 + c1));

    o[0] = dz0 + DTf * (DRIVE * s0 + COUPLE * (dz1 + ex) - DAMP * dz0);
    o[1] = dz1 + DTf * (DRIVE * s1 + COUPLE * (dz0 + ex) - DAMP * dz1);

    float to[3];
#pragma unroll
    for (int i = 0; i < 3; ++i) {
        const float nb = Tm[3 * i + 0] * tzr[0] + Tm[3 * i + 1] * tzr[1]
                       + Tm[3 * i + 2] * tzr[2] + ex;
        const float pn = tpr[i] + (DT_OM_T + ENTRAIN * __sinf(mp - tpr[i]));
        float v = tzr[i] + DTf * (DRIVE * __sinf(pn) + COUPLE * nb - DAMP * tzr[i]);
        v = fminf(fmaxf(v, -GAMMA_F), GAMMA_F);
        to[i] = v;
        o[2 + i] = v;
    }

    const float exq = EXT_SC * ((to[0] + to[1] + to[2]) * (1.0f / 3.0f) * tqc);
#pragma unroll
    for (int i = 0; i < 4; ++i) {
        const float nb = Qm[4 * i + 0] * qzr[0] + Qm[4 * i + 1] * qzr[1]
                       + Qm[4 * i + 2] * qzr[2] + Qm[4 * i + 3] * qzr[3] + exq;
        const float pn = qpr[i] + (DT_OM_Q + ENTRAIN * __sinf(mp - qpr[i]));
        float v = qzr[i] + DTf * (DRIVE * __sinf(pn) + COUPLE * nb - DAMP * qzr[i]);
        v = fminf(fmaxf(v, -GAMMA_F), GAMMA_F);
        o[5 + i] = v;
    }

    o[9] = mp;
}

// load + compute one PAIR (rows 2P, 2P+1) -> o[20]
__device__ __forceinline__ void pair_load_compute(
    int P,
    const float* __restrict__ ext, const float* __restrict__ dz,
    const float* __restrict__ dp,  const float* __restrict__ tz,
    const float* __restrict__ tp,  const float* __restrict__ qz,
    const float* __restrict__ qp,
    const float* Tm, const float* Qm, float tqc, float* o)
{
    const float2 ev  = ((const float2*)ext)[P];
    const float4 dzv = ((const float4*)dz)[P];
    const float4 dpv = ((const float4*)dp)[P];
    const float2 tza = ((const float2*)tz)[3 * P + 0];
    const float2 tzb = ((const float2*)tz)[3 * P + 1];
    const float2 tzc = ((const float2*)tz)[3 * P + 2];
    const float2 tpa = ((const float2*)tp)[3 * P + 0];
    const float2 tpb = ((const float2*)tp)[3 * P + 1];
    const float2 tpc = ((const float2*)tp)[3 * P + 2];
    const float4 qzA = ((const float4*)qz)[2 * P + 0];
    const float4 qzB = ((const float4*)qz)[2 * P + 1];
    const float4 qpA = ((const float4*)qp)[2 * P + 0];
    const float4 qpB = ((const float4*)qp)[2 * P + 1];

    const float tzrA[3] = {tza.x, tza.y, tzb.x};
    const float tzrB[3] = {tzb.y, tzc.x, tzc.y};
    const float tprA[3] = {tpa.x, tpa.y, tpb.x};
    const float tprB[3] = {tpb.y, tpc.x, tpc.y};
    const float qzrA[4] = {qzA.x, qzA.y, qzA.z, qzA.w};
    const float qzrB[4] = {qzB.x, qzB.y, qzB.z, qzB.w};
    const float qprA[4] = {qpA.x, qpA.y, qpA.z, qpA.w};
    const float qprB[4] = {qpB.x, qpB.y, qpB.z, qpB.w};

    row_compute(ev.x, dzv.x, dzv.y, dpv.x, dpv.y,
                tzrA, tprA, qzrA, qprA, Tm, Qm, tqc, o);
    row_compute(ev.y, dzv.z, dzv.w, dpv.z, dpv.w,
                tzrB, tprB, qzrB, qprB, Tm, Qm, tqc, o + 10);
}

// ---------------- variant A: LDS-staged coalesced nt store (R4 structure) ----
__global__ __launch_bounds__(BLOCK) void genesis_lds(
    const float* __restrict__ ext, const float* __restrict__ dz,
    const float* __restrict__ dp,  const float* __restrict__ tz,
    const float* __restrict__ tp,  const float* __restrict__ qz,
    const float* __restrict__ qp,  const float* __restrict__ tcm,
    const float* __restrict__ qcm, const float* __restrict__ tqs,
    float* __restrict__ out, int rowBase, int B)
{
    __shared__ float so[BLOCK * PPAD];

    const int t    = threadIdx.x;
    const int base = rowBase + blockIdx.x * RPB;
    const int g    = base / 2 + t;

    float Tm[9], Qm[16];
#pragma unroll
    for (int i = 0; i < 9; ++i) Tm[i] = tcm[i];
#pragma unroll
    for (int i = 0; i < 16; ++i) Qm[i] = qcm[i];
    const float tqc = tqs[0];

    const int rows = min(RPB, B - base);

    if (rows == RPB) {
        float o[20];
        pair_load_compute(g, ext, dz, dp, tz, tp, qz, qp, Tm, Qm, tqc, o);
#pragma unroll
        for (int k = 0; k < 20; ++k) so[PPAD * t + k] = o[k];
        __syncthreads();

        f32x4* outV = (f32x4*)(out + (size_t)base * 10);
        constexpr int NF4 = RPB * 10 / 4;               // 1280
#pragma unroll
        for (int c = t; c < NF4; c += BLOCK) {
            const int e0 = 4 * c;                       // e0%20 in {0,4,8,12,16}
            const int lb = PPAD * (e0 / 20) + (e0 % 20);
            f32x4 v;
            v.x = so[lb + 0]; v.y = so[lb + 1];
            v.z = so[lb + 2]; v.w = so[lb + 3];
            __builtin_nontemporal_store(v, outV + c);
        }
    } else if (rows > 0) {
#pragma unroll
        for (int r = 0; r < 2; ++r) {
            const int lr = 2 * t + r;
            if (lr < rows) {
                const int b = base + lr;
                const float tzr[3] = {tz[3 * b], tz[3 * b + 1], tz[3 * b + 2]};
                const float tpr[3] = {tp[3 * b], tp[3 * b + 1], tp[3 * b + 2]};
                const float qzr[4] = {qz[4 * b], qz[4 * b + 1], qz[4 * b + 2], qz[4 * b + 3]};
                const float qpr[4] = {qp[4 * b], qp[4 * b + 1], qp[4 * b + 2], qp[4 * b + 3]};
                float o[10];
                row_compute(ext[b], dz[2 * b], dz[2 * b + 1], dp[2 * b], dp[2 * b + 1],
                            tzr, tpr, qzr, qpr, Tm, Qm, tqc, o);
                const int pb = PPAD * t + 10 * r;
                for (int k = 0; k < 10; ++k) so[pb + k] = o[k];
            }
        }
        __syncthreads();
        const int nf = rows * 10;
        for (int k = t; k < nf; k += BLOCK) {
            out[(size_t)base * 10 + k] = so[PPAD * (k / 20) + (k % 20)];
        }
    }
}

// ---------------- variant B: direct strided f32x4 stores, no LDS/barrier ----
__global__ __launch_bounds__(BLOCK) void genesis_direct(
    const float* __restrict__ ext, const float* __restrict__ dz,
    const float* __restrict__ dp,  const float* __restrict__ tz,
    const float* __restrict__ tp,  const float* __restrict__ qz,
    const float* __restrict__ qp,  const float* __restrict__ tcm,
    const float* __restrict__ qcm, const float* __restrict__ tqs,
    float* __restrict__ out, int rowBase, int B)
{
    const int t    = threadIdx.x;
    const int base = rowBase + blockIdx.x * RPB;
    const int g    = base / 2 + t;

    float Tm[9], Qm[16];
#pragma unroll
    for (int i = 0; i < 9; ++i) Tm[i] = tcm[i];
#pragma unroll
    for (int i = 0; i < 16; ++i) Qm[i] = qcm[i];
    const float tqc = tqs[0];

    const int rows = min(RPB, B - base);

    if (rows == RPB) {
        float o[20];
        pair_load_compute(g, ext, dz, dp, tz, tp, qz, qp, Tm, Qm, tqc, o);
        // direct stores: 5 x f32x4 per pair, lane stride 80 B. Cached (not nt)
        // so L2 merges partial lines; HBM write bytes should stay ideal.
        f32x4* outV = (f32x4*)(out + (size_t)g * 20);
#pragma unroll
        for (int j = 0; j < 5; ++j) {
            f32x4 v;
            v.x = o[4 * j + 0]; v.y = o[4 * j + 1];
            v.z = o[4 * j + 2]; v.w = o[4 * j + 3];
            outV[j] = v;
        }
    } else if (rows > 0) {
#pragma unroll
        for (int r = 0; r < 2; ++r) {
            const int lr = 2 * t + r;
            if (lr < rows) {
                const int b = base + lr;
                const float tzr[3] = {tz[3 * b], tz[3 * b + 1], tz[3 * b + 2]};
                const float tpr[3] = {tp[3 * b], tp[3 * b + 1], tp[3 * b + 2]};
                const float qzr[4] = {qz[4 * b], qz[4 * b + 1], qz[4 * b + 2], qz[4 * b + 3]};
                const float qpr[4] = {qp[4 * b], qp[4 * b + 1], qp[4 * b + 2], qp[4 * b + 3]};
                float o[10];
                row_compute(ext[b], dz[2 * b], dz[2 * b + 1], dp[2 * b], dp[2 * b + 1],
                            tzr, tpr, qzr, qpr, Tm, Qm, tqc, o);
                for (int k = 0; k < 10; ++k) out[(size_t)b * 10 + k] = o[k];
            }
        }
    }
}

extern "C" void kernel_launch(void* const* d_in, const int* in_sizes, int n_in,
                              void* d_out, int out_size, void* d_ws, size_t ws_size,
                              hipStream_t stream)
{
    const float* ext = (const float*)d_in[0];
    const float* dz  = (const float*)d_in[1];
    const float* dp  = (const float*)d_in[2];
    const float* tz  = (const float*)d_in[3];
    const float* tp  = (const float*)d_in[4];
    const float* qz  = (const float*)d_in[5];
    const float* qp  = (const float*)d_in[6];
    const float* tcm = (const float*)d_in[7];
    const float* qcm = (const float*)d_in[8];
    const float* tqs = (const float*)d_in[9];

    const int B = in_sizes[0];

    // split rows in half (512-aligned) for within-probe A/B of store paths
    int NA = ((B / 2) / RPB) * RPB;
    if (NA < 0) NA = 0;
    const int NB = B - NA;

    if (NA > 0) {
        const int gridA = NA / RPB;
        genesis_lds<<<gridA, BLOCK, 0, stream>>>(ext, dz, dp, tz, tp, qz, qp,
                                                 tcm, qcm, tqs,
                                                 (float*)d_out, 0, NA);
    }
    if (NB > 0) {
        const int gridB = (NB + RPB - 1) / RPB;
        genesis_direct<<<gridB, BLOCK, 0, stream>>>(ext, dz, dp, tz, tp, qz, qp,
                                                    tcm, qcm, tqs,
                                                    (float*)d_out, NA, B);
    }
}

// Round 7
// 74.833 us; speedup vs baseline: 1.3075x; 1.3075x over previous
//
#include <hip/hip_runtime.h>
#include <math.h>

// ---------------- constants (match reference, f32-cast like np.float32) -----
namespace {
constexpr float DTf     = 0.01f;
constexpr float GAMMA_F = 0.103f;
constexpr float DRIVE   = 0.1f;
constexpr float COUPLE  = 0.1f;
constexpr float DAMP    = 0.01f;
constexpr float ENTRAIN = 0.1f;
constexpr float EXT_SC  = 0.1f;

constexpr double PHI    = 1.618033988749895;
constexpr double TWO_PI = 6.283185307179586476925287;
constexpr double PHI2   = PHI * PHI;
constexpr double PHI4   = PHI2 * PHI2;
constexpr double PHI5   = PHI4 * PHI;
constexpr double PHI7   = PHI5 * PHI2;
constexpr double PHI11  = PHI7 * PHI4;

constexpr float OMEGA_D = (float)(TWO_PI / (40.0 * PHI11));
constexpr float OMEGA_T = (float)(TWO_PI / (40.0 * PHI7));
constexpr float OMEGA_Q = (float)(TWO_PI / (40.0 * PHI5));
constexpr float DT_OM_D = DTf * OMEGA_D;
constexpr float DT_OM_T = DTf * OMEGA_T;
constexpr float DT_OM_Q = DTf * OMEGA_Q;

constexpr int BLOCK = 256;
constexpr int RPT   = 2;                 // rows per thread
constexpr int RPB   = BLOCK * RPT;       // 512 rows per block
constexpr int PPAD  = 21;                // LDS floats per 2-row pair (20 + 1 pad), gcd(21,32)=1

typedef float f32x4 __attribute__((ext_vector_type(4)));  // clang vector: ok for nontemporal builtin
}

// One row. o[0..9] = {d0,d1,t0,t1,t2,q0..q3,mean_phase}
// NOTE: D-path numerics (sinf/cosf/atan2f) must stay EXACTLY as the passing
// version (absmax 0.0430 vs threshold 0.0628 depends on it). T/Q use __sinf:
// their sin contributions are scaled by <=1e-3 into the output.
//
// PERF NOTE (R4-R6 evidence): this structure is at 98% of the 6.29 TB/s
// combined-traffic ceiling (464 MB app bytes / 75.1 us). Tested and rejected:
// 4 rows/thread up-front MLP (77.1 us, R5); direct strided f32x4 stores
// without LDS staging (~1.6x worse store path, R6). Do not "improve" the
// store path without re-running the R6 A/B.
__device__ __forceinline__ void row_compute(
    float e,
    float dz0, float dz1, float dp0, float dp1,
    const float* tzr, const float* tpr,
    const float* qzr, const float* qpr,
    const float* Tm, const float* Qm, float tqc,
    float* o)
{
    const float ex = EXT_SC * e;

    // ---- D module (master clock, unbounded). Precise trig: feeds atan2. ----
    const float dpn0 = dp0 + DT_OM_D;
    const float dpn1 = dp1 + DT_OM_D;
    const float s0 = sinf(dpn0), c0 = cosf(dpn0);
    const float s1 = sinf(dpn1), c1 = cosf(dpn1);
    const float mp = atan2f(0.5f * (s0 + s1), 0.5f * (c0 + c1));

    o[0] = dz0 + DTf * (DRIVE * s0 + COUPLE * (dz1 + ex) - DAMP * dz0);
    o[1] = dz1 + DTf * (DRIVE * s1 + COUPLE * (dz0 + ex) - DAMP * dz1);

    // ---- T module ----
    float to[3];
#pragma unroll
    for (int i = 0; i < 3; ++i) {
        const float nb = Tm[3 * i + 0] * tzr[0] + Tm[3 * i + 1] * tzr[1]
                       + Tm[3 * i + 2] * tzr[2] + ex;
        const float pn = tpr[i] + (DT_OM_T + ENTRAIN * __sinf(mp - tpr[i]));
        float v = tzr[i] + DTf * (DRIVE * __sinf(pn) + COUPLE * nb - DAMP * tzr[i]);
        v = fminf(fmaxf(v, -GAMMA_F), GAMMA_F);
        to[i] = v;
        o[2 + i] = v;
    }

    // ---- Q module ----
    const float exq = EXT_SC * ((to[0] + to[1] + to[2]) * (1.0f / 3.0f) * tqc);
#pragma unroll
    for (int i = 0; i < 4; ++i) {
        const float nb = Qm[4 * i + 0] * qzr[0] + Qm[4 * i + 1] * qzr[1]
                       + Qm[4 * i + 2] * qzr[2] + Qm[4 * i + 3] * qzr[3] + exq;
        const float pn = qpr[i] + (DT_OM_Q + ENTRAIN * __sinf(mp - qpr[i]));
        float v = qzr[i] + DTf * (DRIVE * __sinf(pn) + COUPLE * nb - DAMP * qzr[i]);
        v = fminf(fmaxf(v, -GAMMA_F), GAMMA_F);
        o[5 + i] = v;
    }

    o[9] = mp;
}

__global__ __launch_bounds__(BLOCK) void genesis_kernel(
    const float* __restrict__ ext,
    const float* __restrict__ dz,
    const float* __restrict__ dp,
    const float* __restrict__ tz,
    const float* __restrict__ tp,
    const float* __restrict__ qz,
    const float* __restrict__ qp,
    const float* __restrict__ tcm,
    const float* __restrict__ qcm,
    const float* __restrict__ tqs,
    float* __restrict__ out,
    int B)
{
    __shared__ float so[BLOCK * PPAD];   // 21.5 KB

    const int t    = threadIdx.x;
    const int base = blockIdx.x * RPB;   // first row of this block
    const int g    = blockIdx.x * BLOCK + t;   // this thread's row-PAIR index

    float Tm[9], Qm[16];
#pragma unroll
    for (int i = 0; i < 9; ++i) Tm[i] = tcm[i];
#pragma unroll
    for (int i = 0; i < 16; ++i) Qm[i] = qcm[i];
    const float tqc = tqs[0];

    const int rows = min(RPB, B - base); // rows valid in this block

    if (rows == RPB) {
        // ---------- full block: vectorized 2-rows-per-thread ----------
        const float2 ev  = ((const float2*)ext)[g];
        const float4 dzv = ((const float4*)dz)[g];
        const float4 dpv = ((const float4*)dp)[g];
        const float2* tz2 = (const float2*)(tz + 6 * (size_t)g);
        const float2* tp2 = (const float2*)(tp + 6 * (size_t)g);
        const float2 tza = tz2[0], tzb = tz2[1], tzc = tz2[2];
        const float2 tpa = tp2[0], tpb = tp2[1], tpc = tp2[2];
        const float4 qzA = ((const float4*)qz)[2 * g + 0];
        const float4 qzB = ((const float4*)qz)[2 * g + 1];
        const float4 qpA = ((const float4*)qp)[2 * g + 0];
        const float4 qpB = ((const float4*)qp)[2 * g + 1];

        const float tzrA[3] = {tza.x, tza.y, tzb.x};
        const float tzrB[3] = {tzb.y, tzc.x, tzc.y};
        const float tprA[3] = {tpa.x, tpa.y, tpb.x};
        const float tprB[3] = {tpb.y, tpc.x, tpc.y};
        const float qzrA[4] = {qzA.x, qzA.y, qzA.z, qzA.w};
        const float qzrB[4] = {qzB.x, qzB.y, qzB.z, qzB.w};
        const float qprA[4] = {qpA.x, qpA.y, qpA.z, qpA.w};
        const float qprB[4] = {qpB.x, qpB.y, qpB.z, qpB.w};

        float oA[10], oB[10];
        row_compute(ev.x, dzv.x, dzv.y, dpv.x, dpv.y,
                    tzrA, tprA, qzrA, qprA, Tm, Qm, tqc, oA);
        row_compute(ev.y, dzv.z, dzv.w, dpv.z, dpv.w,
                    tzrB, tprB, qzrB, qprB, Tm, Qm, tqc, oB);

#pragma unroll
        for (int k = 0; k < 10; ++k) so[PPAD * t + k]      = oA[k];
#pragma unroll
        for (int k = 0; k < 10; ++k) so[PPAD * t + 10 + k] = oB[k];

        __syncthreads();

        // cooperative, coalesced nontemporal float4 store (write-once data:
        // nt keeps the output from evicting inputs out of L3)
        f32x4* outV = (f32x4*)(out + (size_t)base * 10);   // 16B-aligned (base%512==0)
        constexpr int NF4 = RPB * 10 / 4;                  // 1280 float4 per block
#pragma unroll
        for (int c = t; c < NF4; c += BLOCK) {
            const int e0 = 4 * c;                  // e0%20 in {0,4,8,12,16}: never crosses pair
            const int lb = PPAD * (e0 / 20) + (e0 % 20);
            f32x4 v;
            v.x = so[lb + 0];
            v.y = so[lb + 1];
            v.z = so[lb + 2];
            v.w = so[lb + 3];
            __builtin_nontemporal_store(v, outV + c);
        }
    } else {
        // ---------- tail block: scalar per-row path ----------
#pragma unroll
        for (int r = 0; r < RPT; ++r) {
            const int lr = RPT * t + r;       // local row
            if (lr < rows) {
                const int b = base + lr;
                const float tzr[3] = {tz[3 * b], tz[3 * b + 1], tz[3 * b + 2]};
                const float tpr[3] = {tp[3 * b], tp[3 * b + 1], tp[3 * b + 2]};
                const float qzr[4] = {qz[4 * b], qz[4 * b + 1], qz[4 * b + 2], qz[4 * b + 3]};
                const float qpr[4] = {qp[4 * b], qp[4 * b + 1], qp[4 * b + 2], qp[4 * b + 3]};
                float o[10];
                row_compute(ext[b], dz[2 * b], dz[2 * b + 1], dp[2 * b], dp[2 * b + 1],
                            tzr, tpr, qzr, qpr, Tm, Qm, tqc, o);
                const int pairBase = PPAD * t + 10 * r;
                for (int k = 0; k < 10; ++k) so[pairBase + k] = o[k];
            }
        }
        __syncthreads();
        if (rows > 0) {
            const int nf = rows * 10;
            for (int k = t; k < nf; k += BLOCK) {
                out[(size_t)base * 10 + k] = so[PPAD * (k / 20) + (k % 20)];
            }
        }
    }
}

extern "C" void kernel_launch(void* const* d_in, const int* in_sizes, int n_in,
                              void* d_out, int out_size, void* d_ws, size_t ws_size,
                              hipStream_t stream)
{
    const float* ext = (const float*)d_in[0];
    const float* dz  = (const float*)d_in[1];
    const float* dp  = (const float*)d_in[2];
    const float* tz  = (const float*)d_in[3];
    const float* tp  = (const float*)d_in[4];
    const float* qz  = (const float*)d_in[5];
    const float* qp  = (const float*)d_in[6];
    const float* tcm = (const float*)d_in[7];
    const float* qcm = (const float*)d_in[8];
    const float* tqs = (const float*)d_in[9];

    const int B = in_sizes[0];
    int grid = (B + RPB - 1) / RPB;
    if (grid < 1) grid = 1;

    genesis_kernel<<<grid, BLOCK, 0, stream>>>(ext, dz, dp, tz, tp, qz, qp,
                                               tcm, qcm, tqs,
                                               (float*)d_out, B);
}